// Round 5
// baseline (48.004 us; speedup 1.0000x reference)
//
#include <hip/hip_runtime.h>
#include <hip/hip_bf16.h>

#define B_  256
#define T_  256
#define C_  384
#define HS_ 64
#define BT_ (B_*T_)

typedef __attribute__((ext_vector_type(8))) short short8;
typedef __attribute__((ext_vector_type(4))) float f32x4;

// ---------- helpers ----------
__device__ __forceinline__ unsigned short f2bf(float f) {
    unsigned u = __float_as_uint(f);
    u += 0x7FFFu + ((u >> 16) & 1u);   // round-to-nearest-even
    return (unsigned short)(u >> 16);
}

// ---------- kernel 0: W -> Wt[192][384] bf16 (transposed, Q|K|V stacked) ----------
// Q columns pre-scaled by 384^-0.5 (reference scales scores by C^-0.5).
__global__ __launch_bounds__(256) void prep_w(
    const float* __restrict__ Wq, const float* __restrict__ Wk,
    const float* __restrict__ Wv, unsigned short* __restrict__ Wt)
{
    int i = blockIdx.x * 256 + threadIdx.x;     // 192*384 = 73728 exactly
    int n = i / C_, k = i - n * C_;
    const float* src = (n < 64) ? Wq : (n < 128) ? Wk : Wv;
    float v = src[(size_t)k * HS_ + (n & 63)];
    if (n < 64) v *= 0.05103103630798288f;
    Wt[i] = f2bf(v);
}

// ---------- fused kernel: QKV projection + causal flash attention ----------
// One block per batch, 1024 thr = 16 waves (4 waves/SIMD for latency hiding).
// GEMM: M=256 x N=192 x K=384; wave (wm,wn) owns rows wm*64..+64, cols wn*48..+48.
// W frags straight from L2 (never staged). Attention: one 16-row q-tile per wave,
// SIMD-balanced assignment, zero block syncs in the kv loop.
// LDS map (u16 units):
//   Qs  [256][72]  @ 0       (18432)
//   Ks  [256][72]  @ 18432   (18432)
//   Vts [64][264]  @ 36864   (16896)   V transposed: [h][tok]
//   Xs  [2][256][40] @ 53760 (20480)   GEMM staging; P aliases buf0 in attn
// total 74240 u16 = 148480 B
#define LQ_OFF 0
#define LK_OFF 18432
#define LV_OFF 36864
#define LX_OFF 53760
#define LDSP   40

__global__ __launch_bounds__(1024, 4) void head_fused(
    const float* __restrict__ X, const unsigned short* __restrict__ Wt,
    float* __restrict__ out)
{
    __shared__ unsigned short lds[74240];
    const int t    = threadIdx.x;
    const int w    = t >> 6;        // 0..15
    const int lane = t & 63;
    const int lo   = lane & 15;
    const int hi   = lane >> 4;
    const int b    = blockIdx.x;
    const int wm   = w >> 2, wn = w & 3;

    const float* Xb = X + (size_t)b * T_ * C_;

    // ================= phase 1: QKV GEMM =================
    const int srow  = t >> 2;       // 0..255
    const int squad = t & 3;        // 8-float chunk of the 32-k slice

    auto stage_load = [&](int k0, float4* g) {
        const float* p = Xb + (size_t)srow * C_ + k0 + squad * 8;
        g[0] = *(const float4*)(p);
        g[1] = *(const float4*)(p + 4);
    };
    auto stage_write = [&](int buf, const float4* g) {
        short8 p;
        p[0] = (short)f2bf(g[0].x); p[1] = (short)f2bf(g[0].y);
        p[2] = (short)f2bf(g[0].z); p[3] = (short)f2bf(g[0].w);
        p[4] = (short)f2bf(g[1].x); p[5] = (short)f2bf(g[1].y);
        p[6] = (short)f2bf(g[1].z); p[7] = (short)f2bf(g[1].w);
        *(short8*)&lds[LX_OFF + buf * 10240 + srow * 40 + squad * 8] = p;
    };
    auto load_w = [&](int k0, short8* wf) {    // B-frag: col=wn*48+f*16+lo, k=hi*8+j
        #pragma unroll
        for (int f = 0; f < 3; ++f)
            wf[f] = *(const short8*)(Wt + (size_t)(wn * 48 + f * 16 + lo) * C_ + k0 + hi * 8);
    };

    float4 g[2];
    short8 wf[3];
    stage_load(0, g);
    load_w(0, wf);
    stage_write(0, g);
    __syncthreads();

    f32x4 acc[4][3];
    #pragma unroll
    for (int m = 0; m < 4; ++m)
        #pragma unroll
        for (int f = 0; f < 3; ++f)
            acc[m][f] = (f32x4){0.f, 0.f, 0.f, 0.f};

    #pragma unroll 2
    for (int s = 0; s < 12; ++s) {
        const int cur = s & 1;
        float4 gn[2];
        short8 wfn[3];
        if (s < 11) {                               // issue next-step loads early (T14)
            stage_load((s + 1) * 32, gn);
            load_w((s + 1) * 32, wfn);
        }
        short8 af[4];                               // A-frag: row=lo, k=hi*8+j
        #pragma unroll
        for (int m = 0; m < 4; ++m)
            af[m] = *(const short8*)&lds[LX_OFF + cur * 10240 + (wm * 64 + m * 16 + lo) * 40 + hi * 8];
        #pragma unroll
        for (int m = 0; m < 4; ++m)
            #pragma unroll
            for (int f = 0; f < 3; ++f)
                acc[m][f] = __builtin_amdgcn_mfma_f32_16x16x32_bf16(af[m], wf[f], acc[m][f], 0, 0, 0);
        if (s < 11) {
            stage_write(cur ^ 1, gn);
            wf[0] = wfn[0]; wf[1] = wfn[1]; wf[2] = wfn[2];
        }
        __syncthreads();
    }

    // epilogue: D col = wn*48+f*16+lo, row = wm*64+m*16+hi*4+r  -> LDS Q/K/Vt
    #pragma unroll
    for (int m = 0; m < 4; ++m) {
        const int rowb = wm * 64 + m * 16 + hi * 4;
        #pragma unroll
        for (int f = 0; f < 3; ++f) {
            const int base = wn * 48 + f * 16;      // frag fully inside one of Q/K/V
            if (base < 64) {
                #pragma unroll
                for (int r = 0; r < 4; ++r)
                    lds[LQ_OFF + (rowb + r) * 72 + base + lo] = f2bf(acc[m][f][r]);
            } else if (base < 128) {
                #pragma unroll
                for (int r = 0; r < 4; ++r)
                    lds[LK_OFF + (rowb + r) * 72 + (base - 64) + lo] = f2bf(acc[m][f][r]);
            } else {
                ushort4 pk = { f2bf(acc[m][f][0]), f2bf(acc[m][f][1]),
                               f2bf(acc[m][f][2]), f2bf(acc[m][f][3]) };
                *(ushort4*)&lds[LV_OFF + (base - 128 + lo) * 264 + rowb] = pk;
            }
        }
    }
    __syncthreads();

    // ================= phase 2: causal flash attention =================
    unsigned short* Pw = &lds[LX_OFF + w * 640];    // aliases dead X staging (buf0+buf1)

    // SIMD-balanced tile assignment (wave->SIMD assumed w&3):
    // SIMD g gets tiles {g, 15-g, 4+g, 11-g} -> 18 kv-steps each.
    const int sg  = w & 3, pos = w >> 2;
    const int tq  = (pos == 0) ? sg : (pos == 1) ? 15 - sg : (pos == 2) ? 4 + sg : 11 - sg;

    {
        short8 qf0 = *(const short8*)&lds[LQ_OFF + (tq * 16 + lo) * 72 + hi * 8];
        short8 qf1 = *(const short8*)&lds[LQ_OFF + (tq * 16 + lo) * 72 + hi * 8 + 32];

        f32x4 acc_o[4];
        #pragma unroll
        for (int n = 0; n < 4; ++n) acc_o[n] = (f32x4){0.f, 0.f, 0.f, 0.f};
        float Mr[4] = {-1e30f, -1e30f, -1e30f, -1e30f};
        float Lr[4] = {0.f, 0.f, 0.f, 0.f};

        const int nsteps = (tq >> 1) + 1;
        for (int s = 0; s < nsteps; ++s) {
            const int kv0 = s * 32;
            f32x4 sa[2];
            sa[0] = (f32x4){0.f, 0.f, 0.f, 0.f};
            sa[1] = (f32x4){0.f, 0.f, 0.f, 0.f};
            #pragma unroll
            for (int n = 0; n < 2; ++n) {
                const unsigned short* kb = &lds[LK_OFF + (kv0 + n * 16 + lo) * 72 + hi * 8];
                short8 kf0 = *(const short8*)kb;
                short8 kf1 = *(const short8*)(kb + 32);
                sa[n] = __builtin_amdgcn_mfma_f32_16x16x32_bf16(qf0, kf0, sa[n], 0, 0, 0);
                sa[n] = __builtin_amdgcn_mfma_f32_16x16x32_bf16(qf1, kf1, sa[n], 0, 0, 0);
            }
            if (s == nsteps - 1) {                  // causal mask
                #pragma unroll
                for (int n = 0; n < 2; ++n)
                    #pragma unroll
                    for (int r = 0; r < 4; ++r) {
                        int kv = kv0 + n * 16 + lo;
                        int q  = tq * 16 + hi * 4 + r;
                        if (kv > q) sa[n][r] = -1e30f;
                    }
            }
            #pragma unroll
            for (int r = 0; r < 4; ++r) {
                float m = fmaxf(sa[0][r], sa[1][r]);
                m = fmaxf(m, __shfl_xor(m, 1));
                m = fmaxf(m, __shfl_xor(m, 2));
                m = fmaxf(m, __shfl_xor(m, 4));
                m = fmaxf(m, __shfl_xor(m, 8));
                float Mn = fmaxf(Mr[r], m);
                float fr = __expf(Mr[r] - Mn);
                Mr[r] = Mn;
                float p0 = __expf(sa[0][r] - Mn);
                float p1 = __expf(sa[1][r] - Mn);
                float ls = p0 + p1;
                ls += __shfl_xor(ls, 1);
                ls += __shfl_xor(ls, 2);
                ls += __shfl_xor(ls, 4);
                ls += __shfl_xor(ls, 8);
                Lr[r] = Lr[r] * fr + ls;
                #pragma unroll
                for (int n = 0; n < 4; ++n) acc_o[n][r] *= fr;
                Pw[(hi * 4 + r) * LDSP + lo]      = f2bf(p0);
                Pw[(hi * 4 + r) * LDSP + 16 + lo] = f2bf(p1);
            }
            short8 pf = *(const short8*)&Pw[lo * LDSP + hi * 8];
            #pragma unroll
            for (int n = 0; n < 4; ++n) {
                short8 vf = *(const short8*)&lds[LV_OFF + (n * 16 + lo) * 264 + kv0 + hi * 8];
                acc_o[n] = __builtin_amdgcn_mfma_f32_16x16x32_bf16(pf, vf, acc_o[n], 0, 0, 0);
            }
        }
        #pragma unroll
        for (int r = 0; r < 4; ++r) {
            float inv = 1.0f / Lr[r];
            float* op = out + ((size_t)(b * 256 + tq * 16 + hi * 4 + r)) * HS_ + lo;
            #pragma unroll
            for (int n = 0; n < 4; ++n)
                op[n * 16] = acc_o[n][r] * inv;
        }
    }
}

// ---------- launch ----------
extern "C" void kernel_launch(void* const* d_in, const int* in_sizes, int n_in,
                              void* d_out, int out_size, void* d_ws, size_t ws_size,
                              hipStream_t stream) {
    const float* X  = (const float*)d_in[0];
    const float* Wq = (const float*)d_in[1];
    const float* Wk = (const float*)d_in[2];
    const float* Wv = (const float*)d_in[3];
    float* out = (float*)d_out;

    unsigned short* Wt = (unsigned short*)d_ws;    // 192*384 bf16 = 144 KB

    prep_w<<<(192 * C_) / 256, 256, 0, stream>>>(Wq, Wk, Wv, Wt);
    head_fused<<<B_, 1024, 0, stream>>>(X, Wt, out);
}

// Round 6
// 41.302 us; speedup vs baseline: 1.1623x; 1.1623x over previous
//
#include <hip/hip_runtime.h>
#include <hip/hip_bf16.h>

#define B_  256
#define T_  256
#define C_  384
#define HS_ 64
#define BT_ (B_*T_)

typedef __attribute__((ext_vector_type(8))) short short8;
typedef __attribute__((ext_vector_type(4))) float f32x4;

// ---------- helpers ----------
__device__ __forceinline__ unsigned short f2bf(float f) {
    unsigned u = __float_as_uint(f);
    u += 0x7FFFu + ((u >> 16) & 1u);   // round-to-nearest-even
    return (unsigned short)(u >> 16);
}

// ---------- kernel 0: W -> MFMA-fragment-ordered bf16 ----------
// Wfrag[s][wn][f][lane] (short8): the exact B-fragment wave (wm,wn) needs at
// K-step s, frag f. Element: col n = wn*48+f*16+(lane&15), k = s*32+(lane>>4)*8+j.
// Main-loop loads become fully-coalesced 1KB global_load_dwordx4 (no gather).
// Q columns pre-scaled by 384^-0.5 (reference scales scores by C^-0.5).
__global__ __launch_bounds__(256) void prep_wfrag(
    const float* __restrict__ Wq, const float* __restrict__ Wk,
    const float* __restrict__ Wv, unsigned short* __restrict__ Wfrag)
{
    const int tid  = blockIdx.x * 256 + threadIdx.x;   // 9216 threads
    const int lane = tid & 63;
    const int q    = tid >> 6;
    const int f    = q % 3;
    const int q2   = q / 3;
    const int wn   = q2 & 3;
    const int s    = q2 >> 2;

    const int n     = wn * 48 + f * 16 + (lane & 15);
    const int kbase = s * 32 + (lane >> 4) * 8;
    const float* src = (n < 64) ? Wq : (n < 128) ? Wk : Wv;
    const int c      = n & 63;
    const float scale = (n < 64) ? 0.05103103630798288f : 1.0f;

    short8 out;
    #pragma unroll
    for (int j = 0; j < 8; ++j)
        out[j] = (short)f2bf(src[(size_t)(kbase + j) * HS_ + c] * scale);
    *(short8*)&Wfrag[(size_t)tid * 8] = out;
}

// ---------- fused kernel: QKV projection + causal flash attention ----------
// One block per batch, 1024 thr = 16 waves (4 waves/SIMD).
// GEMM: M=256 x N=192 x K=384; wave (wm,wn) owns rows wm*64..+64, cols wn*48..+48.
// W fragments loaded coalesced from L2 (fragment-ordered, never staged).
// Attention: one 16-row q-tile per wave, SIMD-balanced, no block syncs in kv loop.
// LDS map (u16 units):
//   Qs  [256][72]  @ 0       (18432)
//   Ks  [256][72]  @ 18432   (18432)
//   Vts [64][264]  @ 36864   (16896)   V transposed: [h][tok]
//   Xs  [2][256][40] @ 53760 (20480)   GEMM staging; P aliases it in attn
// total 74240 u16 = 148480 B
#define LQ_OFF 0
#define LK_OFF 18432
#define LV_OFF 36864
#define LX_OFF 53760
#define LDSP   40

__global__ __launch_bounds__(1024, 4) void head_fused(
    const float* __restrict__ X, const unsigned short* __restrict__ Wfrag,
    float* __restrict__ out)
{
    __shared__ unsigned short lds[74240];
    const int t    = threadIdx.x;
    const int w    = t >> 6;        // 0..15
    const int lane = t & 63;
    const int lo   = lane & 15;
    const int hi   = lane >> 4;
    const int b    = blockIdx.x;
    const int wm   = w >> 2, wn = w & 3;

    const float* Xb = X + (size_t)b * T_ * C_;
    const short8* Wf = (const short8*)Wfrag;

    // ================= phase 1: QKV GEMM =================
    const int srow  = t >> 2;       // 0..255
    const int squad = t & 3;        // 8-float chunk of the 32-k slice

    auto stage_load = [&](int k0, float4* g) {
        const float* p = Xb + (size_t)srow * C_ + k0 + squad * 8;
        g[0] = *(const float4*)(p);
        g[1] = *(const float4*)(p + 4);
    };
    auto stage_write = [&](int buf, const float4* g) {
        short8 p;
        p[0] = (short)f2bf(g[0].x); p[1] = (short)f2bf(g[0].y);
        p[2] = (short)f2bf(g[0].z); p[3] = (short)f2bf(g[0].w);
        p[4] = (short)f2bf(g[1].x); p[5] = (short)f2bf(g[1].y);
        p[6] = (short)f2bf(g[1].z); p[7] = (short)f2bf(g[1].w);
        *(short8*)&lds[LX_OFF + buf * 10240 + srow * 40 + squad * 8] = p;
    };
    auto load_w = [&](int s, short8* wf) {      // coalesced fragment loads
        const short8* base = Wf + ((size_t)(s * 4 + wn) * 3) * 64 + lane;
        #pragma unroll
        for (int f = 0; f < 3; ++f)
            wf[f] = base[f * 64];
    };

    float4 g[2];
    short8 wf[3];
    stage_load(0, g);
    load_w(0, wf);
    stage_write(0, g);
    __syncthreads();

    f32x4 acc[4][3];
    #pragma unroll
    for (int m = 0; m < 4; ++m)
        #pragma unroll
        for (int f = 0; f < 3; ++f)
            acc[m][f] = (f32x4){0.f, 0.f, 0.f, 0.f};

    #pragma unroll 2
    for (int s = 0; s < 12; ++s) {
        const int cur = s & 1;
        float4 gn[2];
        short8 wfn[3];
        if (s < 11) {                               // issue next-step loads early (T14)
            stage_load((s + 1) * 32, gn);
            load_w(s + 1, wfn);
        }
        short8 af[4];                               // A-frag: row=lo, k=hi*8+j
        #pragma unroll
        for (int m = 0; m < 4; ++m)
            af[m] = *(const short8*)&lds[LX_OFF + cur * 10240 + (wm * 64 + m * 16 + lo) * 40 + hi * 8];
        #pragma unroll
        for (int m = 0; m < 4; ++m)
            #pragma unroll
            for (int f = 0; f < 3; ++f)
                acc[m][f] = __builtin_amdgcn_mfma_f32_16x16x32_bf16(af[m], wf[f], acc[m][f], 0, 0, 0);
        if (s < 11) {
            stage_write(cur ^ 1, gn);
            wf[0] = wfn[0]; wf[1] = wfn[1]; wf[2] = wfn[2];
        }
        __syncthreads();
    }

    // epilogue: D col = wn*48+f*16+lo, row = wm*64+m*16+hi*4+r  -> LDS Q/K/Vt
    #pragma unroll
    for (int m = 0; m < 4; ++m) {
        const int rowb = wm * 64 + m * 16 + hi * 4;
        #pragma unroll
        for (int f = 0; f < 3; ++f) {
            const int base = wn * 48 + f * 16;      // frag fully inside one of Q/K/V
            if (base < 64) {
                #pragma unroll
                for (int r = 0; r < 4; ++r)
                    lds[LQ_OFF + (rowb + r) * 72 + base + lo] = f2bf(acc[m][f][r]);
            } else if (base < 128) {
                #pragma unroll
                for (int r = 0; r < 4; ++r)
                    lds[LK_OFF + (rowb + r) * 72 + (base - 64) + lo] = f2bf(acc[m][f][r]);
            } else {
                ushort4 pk = { f2bf(acc[m][f][0]), f2bf(acc[m][f][1]),
                               f2bf(acc[m][f][2]), f2bf(acc[m][f][3]) };
                *(ushort4*)&lds[LV_OFF + (base - 128 + lo) * 264 + rowb] = pk;
            }
        }
    }
    __syncthreads();

    // ================= phase 2: causal flash attention =================
    unsigned short* Pw = &lds[LX_OFF + w * 640];    // aliases dead X staging

    // SIMD-balanced tile assignment (wave->SIMD assumed w&3):
    // SIMD g gets tiles {g, 15-g, 4+g, 11-g} -> 18 kv-steps each.
    const int sg  = w & 3, pos = w >> 2;
    const int tq  = (pos == 0) ? sg : (pos == 1) ? 15 - sg : (pos == 2) ? 4 + sg : 11 - sg;

    {
        short8 qf0 = *(const short8*)&lds[LQ_OFF + (tq * 16 + lo) * 72 + hi * 8];
        short8 qf1 = *(const short8*)&lds[LQ_OFF + (tq * 16 + lo) * 72 + hi * 8 + 32];

        f32x4 acc_o[4];
        #pragma unroll
        for (int n = 0; n < 4; ++n) acc_o[n] = (f32x4){0.f, 0.f, 0.f, 0.f};
        float Mr[4] = {-1e30f, -1e30f, -1e30f, -1e30f};
        float Lr[4] = {0.f, 0.f, 0.f, 0.f};

        const int nsteps = (tq >> 1) + 1;
        for (int s = 0; s < nsteps; ++s) {
            const int kv0 = s * 32;
            f32x4 sa[2];
            sa[0] = (f32x4){0.f, 0.f, 0.f, 0.f};
            sa[1] = (f32x4){0.f, 0.f, 0.f, 0.f};
            #pragma unroll
            for (int n = 0; n < 2; ++n) {
                const unsigned short* kb = &lds[LK_OFF + (kv0 + n * 16 + lo) * 72 + hi * 8];
                short8 kf0 = *(const short8*)kb;
                short8 kf1 = *(const short8*)(kb + 32);
                sa[n] = __builtin_amdgcn_mfma_f32_16x16x32_bf16(qf0, kf0, sa[n], 0, 0, 0);
                sa[n] = __builtin_amdgcn_mfma_f32_16x16x32_bf16(qf1, kf1, sa[n], 0, 0, 0);
            }
            if (s == nsteps - 1) {                  // causal mask
                #pragma unroll
                for (int n = 0; n < 2; ++n)
                    #pragma unroll
                    for (int r = 0; r < 4; ++r) {
                        int kv = kv0 + n * 16 + lo;
                        int q  = tq * 16 + hi * 4 + r;
                        if (kv > q) sa[n][r] = -1e30f;
                    }
            }
            #pragma unroll
            for (int r = 0; r < 4; ++r) {
                float m = fmaxf(sa[0][r], sa[1][r]);
                m = fmaxf(m, __shfl_xor(m, 1));
                m = fmaxf(m, __shfl_xor(m, 2));
                m = fmaxf(m, __shfl_xor(m, 4));
                m = fmaxf(m, __shfl_xor(m, 8));
                float Mn = fmaxf(Mr[r], m);
                float fr = __expf(Mr[r] - Mn);
                Mr[r] = Mn;
                float p0 = __expf(sa[0][r] - Mn);
                float p1 = __expf(sa[1][r] - Mn);
                float ls = p0 + p1;
                ls += __shfl_xor(ls, 1);
                ls += __shfl_xor(ls, 2);
                ls += __shfl_xor(ls, 4);
                ls += __shfl_xor(ls, 8);
                Lr[r] = Lr[r] * fr + ls;
                #pragma unroll
                for (int n = 0; n < 4; ++n) acc_o[n][r] *= fr;
                Pw[(hi * 4 + r) * LDSP + lo]      = f2bf(p0);
                Pw[(hi * 4 + r) * LDSP + 16 + lo] = f2bf(p1);
            }
            short8 pf = *(const short8*)&Pw[lo * LDSP + hi * 8];
            #pragma unroll
            for (int n = 0; n < 4; ++n) {
                short8 vf = *(const short8*)&lds[LV_OFF + (n * 16 + lo) * 264 + kv0 + hi * 8];
                acc_o[n] = __builtin_amdgcn_mfma_f32_16x16x32_bf16(pf, vf, acc_o[n], 0, 0, 0);
            }
        }
        #pragma unroll
        for (int r = 0; r < 4; ++r) {
            float inv = 1.0f / Lr[r];
            float* op = out + ((size_t)(b * 256 + tq * 16 + hi * 4 + r)) * HS_ + lo;
            #pragma unroll
            for (int n = 0; n < 4; ++n)
                op[n * 16] = acc_o[n][r] * inv;
        }
    }
}

// ---------- launch ----------
extern "C" void kernel_launch(void* const* d_in, const int* in_sizes, int n_in,
                              void* d_out, int out_size, void* d_ws, size_t ws_size,
                              hipStream_t stream) {
    const float* X  = (const float*)d_in[0];
    const float* Wq = (const float*)d_in[1];
    const float* Wk = (const float*)d_in[2];
    const float* Wv = (const float*)d_in[3];
    float* out = (float*)d_out;

    unsigned short* Wfrag = (unsigned short*)d_ws;   // 12*4*3*64*8 u16 = 144 KB

    prep_wfrag<<<36, 256, 0, stream>>>(Wq, Wk, Wv, Wfrag);
    head_fused<<<B_, 1024, 0, stream>>>(X, Wfrag, out);
}

// Round 7
// 36.472 us; speedup vs baseline: 1.3162x; 1.1324x over previous
//
#include <hip/hip_runtime.h>
#include <hip/hip_bf16.h>

#define B_  256
#define T_  256
#define C_  384
#define HS_ 64
#define BT_ (B_*T_)

typedef __attribute__((ext_vector_type(8))) short short8;
typedef __attribute__((ext_vector_type(4))) float f32x4;

// ---------- helpers ----------
__device__ __forceinline__ unsigned short f2bf(float f) {
    unsigned u = __float_as_uint(f);
    u += 0x7FFFu + ((u >> 16) & 1u);   // round-to-nearest-even
    return (unsigned short)(u >> 16);
}

// ---------- kernel 0: W -> MFMA-fragment-ordered bf16 ----------
// Wfrag[s][wn][f][lane] (short8): the exact B-fragment wave (wm,wn) needs at
// K-step s, frag f. Element: col n = wn*48+f*16+(lane&15), k = s*32+(lane>>4)*8+j.
// Q columns pre-scaled by 384^-0.5 (reference scales scores by C^-0.5).
__global__ __launch_bounds__(256) void prep_wfrag(
    const float* __restrict__ Wq, const float* __restrict__ Wk,
    const float* __restrict__ Wv, unsigned short* __restrict__ Wfrag)
{
    const int tid  = blockIdx.x * 256 + threadIdx.x;   // 9216 threads
    const int lane = tid & 63;
    const int q    = tid >> 6;
    const int f    = q % 3;
    const int q2   = q / 3;
    const int wn   = q2 & 3;
    const int s    = q2 >> 2;

    const int n     = wn * 48 + f * 16 + (lane & 15);
    const int kbase = s * 32 + (lane >> 4) * 8;
    const float* src = (n < 64) ? Wq : (n < 128) ? Wk : Wv;
    const int c      = n & 63;
    const float scale = (n < 64) ? 0.05103103630798288f : 1.0f;

    short8 out;
    #pragma unroll
    for (int j = 0; j < 8; ++j)
        out[j] = (short)f2bf(src[(size_t)(kbase + j) * HS_ + c] * scale);
    *(short8*)&Wfrag[(size_t)tid * 8] = out;
}

// ---------- fused kernel: QKV projection + causal flash attention ----------
// One block per batch, 1024 thr = 16 waves (4 waves/SIMD).
// GEMM: M=256 x N=192 x K=384; wave (wm,wn) owns rows wm*64..+64, cols wn*48..+48.
// Attention (swapped-MFMA form): QK^T = mfma(K,Q) -> lane holds P row q=lo;
// in-lane softmax (4 shfls/step); PV = mfma(V,P) -> O^T, col=q=lo so the
// online rescale is lane-local. One 16-row q-tile per wave, SIMD-balanced,
// zero block syncs in the kv loop.
// LDS map (u16 units):
//   Qs  [256][72]  @ 0       (18432)
//   Ks  [256][72]  @ 18432   (18432)
//   Vts [64][264]  @ 36864   (16896)   V transposed: [h][tok]
//   Xs  [2][256][40] @ 53760 (20480)   GEMM staging; P aliases it in attn
// total 74240 u16 = 148480 B
#define LQ_OFF 0
#define LK_OFF 18432
#define LV_OFF 36864
#define LX_OFF 53760
#define LDSP   40

__global__ __launch_bounds__(1024, 4) void head_fused(
    const float* __restrict__ X, const unsigned short* __restrict__ Wfrag,
    float* __restrict__ out)
{
    __shared__ unsigned short lds[74240];
    const int t    = threadIdx.x;
    const int w    = t >> 6;        // 0..15
    const int lane = t & 63;
    const int lo   = lane & 15;
    const int hi   = lane >> 4;
    const int b    = blockIdx.x;
    const int wm   = w >> 2, wn = w & 3;

    const float* Xb = X + (size_t)b * T_ * C_;
    const short8* Wf = (const short8*)Wfrag;

    // ================= phase 1: QKV GEMM =================
    const int srow  = t >> 2;       // 0..255
    const int squad = t & 3;        // 8-float chunk of the 32-k slice

    auto stage_load = [&](int k0, float4* g) {
        const float* p = Xb + (size_t)srow * C_ + k0 + squad * 8;
        g[0] = *(const float4*)(p);
        g[1] = *(const float4*)(p + 4);
    };
    auto stage_write = [&](int buf, const float4* g) {
        short8 p;
        p[0] = (short)f2bf(g[0].x); p[1] = (short)f2bf(g[0].y);
        p[2] = (short)f2bf(g[0].z); p[3] = (short)f2bf(g[0].w);
        p[4] = (short)f2bf(g[1].x); p[5] = (short)f2bf(g[1].y);
        p[6] = (short)f2bf(g[1].z); p[7] = (short)f2bf(g[1].w);
        *(short8*)&lds[LX_OFF + buf * 10240 + srow * 40 + squad * 8] = p;
    };
    auto load_w = [&](int s, short8* wf) {      // coalesced fragment loads
        const short8* base = Wf + ((size_t)(s * 4 + wn) * 3) * 64 + lane;
        #pragma unroll
        for (int f = 0; f < 3; ++f)
            wf[f] = base[f * 64];
    };

    float4 g[2];
    short8 wf[3];
    stage_load(0, g);
    load_w(0, wf);
    stage_write(0, g);
    __syncthreads();

    f32x4 acc[4][3];
    #pragma unroll
    for (int m = 0; m < 4; ++m)
        #pragma unroll
        for (int f = 0; f < 3; ++f)
            acc[m][f] = (f32x4){0.f, 0.f, 0.f, 0.f};

    #pragma unroll 2
    for (int s = 0; s < 12; ++s) {
        const int cur = s & 1;
        float4 gn[2];
        short8 wfn[3];
        if (s < 11) {                               // issue next-step loads early (T14)
            stage_load((s + 1) * 32, gn);
            load_w(s + 1, wfn);
        }
        short8 af[4];                               // A-frag: row=lo, k=hi*8+j
        #pragma unroll
        for (int m = 0; m < 4; ++m)
            af[m] = *(const short8*)&lds[LX_OFF + cur * 10240 + (wm * 64 + m * 16 + lo) * 40 + hi * 8];
        #pragma unroll
        for (int m = 0; m < 4; ++m)
            #pragma unroll
            for (int f = 0; f < 3; ++f)
                acc[m][f] = __builtin_amdgcn_mfma_f32_16x16x32_bf16(af[m], wf[f], acc[m][f], 0, 0, 0);
        if (s < 11) {
            stage_write(cur ^ 1, gn);
            wf[0] = wfn[0]; wf[1] = wfn[1]; wf[2] = wfn[2];
        }
        __syncthreads();
    }

    // epilogue: D col = wn*48+f*16+lo, row = wm*64+m*16+hi*4+r  -> LDS Q/K/Vt
    #pragma unroll
    for (int m = 0; m < 4; ++m) {
        const int rowb = wm * 64 + m * 16 + hi * 4;
        #pragma unroll
        for (int f = 0; f < 3; ++f) {
            const int base = wn * 48 + f * 16;      // frag fully inside one of Q/K/V
            if (base < 64) {
                #pragma unroll
                for (int r = 0; r < 4; ++r)
                    lds[LQ_OFF + (rowb + r) * 72 + base + lo] = f2bf(acc[m][f][r]);
            } else if (base < 128) {
                #pragma unroll
                for (int r = 0; r < 4; ++r)
                    lds[LK_OFF + (rowb + r) * 72 + (base - 64) + lo] = f2bf(acc[m][f][r]);
            } else {
                ushort4 pk = { f2bf(acc[m][f][0]), f2bf(acc[m][f][1]),
                               f2bf(acc[m][f][2]), f2bf(acc[m][f][3]) };
                *(ushort4*)&lds[LV_OFF + (base - 128 + lo) * 264 + rowb] = pk;
            }
        }
    }
    __syncthreads();

    // ================= phase 2: causal flash attention (swapped MFMA) =================
    unsigned short* Pw = &lds[LX_OFF + w * 640];    // per-wave P tile [16][LDSP]

    // SIMD-balanced tile assignment (wave->SIMD assumed w&3):
    // SIMD g gets tiles {g, 15-g, 4+g, 11-g} -> 18 kv-steps each.
    const int sg  = w & 3, pos = w >> 2;
    const int tq  = (pos == 0) ? sg : (pos == 1) ? 15 - sg : (pos == 2) ? 4 + sg : 11 - sg;

    {
        const int q_lane = tq * 16 + lo;            // this lane's q row
        // Q as B-frag: col=q=lo, k=hi*8+j (+32)
        short8 qf0 = *(const short8*)&lds[LQ_OFF + q_lane * 72 + hi * 8];
        short8 qf1 = *(const short8*)&lds[LQ_OFF + q_lane * 72 + hi * 8 + 32];

        f32x4 acc_o[4];                             // O^T: acc_o[n2][r] = O[h=n2*16+hi*4+r][q=lo]
        #pragma unroll
        for (int n = 0; n < 4; ++n) acc_o[n] = (f32x4){0.f, 0.f, 0.f, 0.f};
        float Mr = -1e30f, Lr = 0.f;

        const int nsteps = (tq >> 1) + 1;
        for (int s = 0; s < nsteps; ++s) {
            const int kv0 = s * 32;
            // QK^T swapped: sb[n] = K-rows x Q-cols; D[row=kv][col=q]
            f32x4 sb[2];
            sb[0] = (f32x4){0.f, 0.f, 0.f, 0.f};
            sb[1] = (f32x4){0.f, 0.f, 0.f, 0.f};
            #pragma unroll
            for (int n = 0; n < 2; ++n) {
                const unsigned short* kb = &lds[LK_OFF + (kv0 + n * 16 + lo) * 72 + hi * 8];
                short8 kf0 = *(const short8*)kb;
                short8 kf1 = *(const short8*)(kb + 32);
                sb[n] = __builtin_amdgcn_mfma_f32_16x16x32_bf16(kf0, qf0, sb[n], 0, 0, 0);
                sb[n] = __builtin_amdgcn_mfma_f32_16x16x32_bf16(kf1, qf1, sb[n], 0, 0, 0);
            }
            if (s == nsteps - 1) {                  // causal: kv = kv0+n*16+hi*4+r
                #pragma unroll
                for (int n = 0; n < 2; ++n)
                    #pragma unroll
                    for (int r = 0; r < 4; ++r)
                        if (kv0 + n * 16 + hi * 4 + r > q_lane) sb[n][r] = -1e30f;
            }
            // in-lane softmax for row q=lo (8 values here, rest across hi groups)
            float pmax = fmaxf(fmaxf(fmaxf(sb[0][0], sb[0][1]), fmaxf(sb[0][2], sb[0][3])),
                               fmaxf(fmaxf(sb[1][0], sb[1][1]), fmaxf(sb[1][2], sb[1][3])));
            pmax = fmaxf(pmax, __shfl_xor(pmax, 16));
            pmax = fmaxf(pmax, __shfl_xor(pmax, 32));
            const float Mn = fmaxf(Mr, pmax);
            const float fr = __expf(Mr - Mn);
            Mr = Mn;
            float p0 = __expf(sb[0][0] - Mn), p1 = __expf(sb[0][1] - Mn);
            float p2 = __expf(sb[0][2] - Mn), p3 = __expf(sb[0][3] - Mn);
            float p4 = __expf(sb[1][0] - Mn), p5 = __expf(sb[1][1] - Mn);
            float p6 = __expf(sb[1][2] - Mn), p7 = __expf(sb[1][3] - Mn);
            float ls = ((p0 + p1) + (p2 + p3)) + ((p4 + p5) + (p6 + p7));
            ls += __shfl_xor(ls, 16);
            ls += __shfl_xor(ls, 32);
            Lr = Lr * fr + ls;
            #pragma unroll
            for (int n = 0; n < 4; ++n) {
                acc_o[n][0] *= fr; acc_o[n][1] *= fr;
                acc_o[n][2] *= fr; acc_o[n][3] *= fr;
            }
            // P -> per-wave LDS tile [q=lo][kv], two b64 writes
            ushort4 w0 = { f2bf(p0), f2bf(p1), f2bf(p2), f2bf(p3) };
            ushort4 w1 = { f2bf(p4), f2bf(p5), f2bf(p6), f2bf(p7) };
            *(ushort4*)&Pw[lo * LDSP + hi * 4]      = w0;
            *(ushort4*)&Pw[lo * LDSP + 16 + hi * 4] = w1;
            // PV swapped: A = Vt rows (h), B = P (col=q); D[row=h][col=q]
            short8 pf = *(const short8*)&Pw[lo * LDSP + hi * 8];
            #pragma unroll
            for (int n = 0; n < 4; ++n) {
                short8 vf = *(const short8*)&lds[LV_OFF + (n * 16 + lo) * 264 + kv0 + hi * 8];
                acc_o[n] = __builtin_amdgcn_mfma_f32_16x16x32_bf16(vf, pf, acc_o[n], 0, 0, 0);
            }
        }
        // epilogue: out[q=q_lane][h=n2*16+hi*4+r] = acc_o[n2][r]/Lr
        const float inv = 1.0f / Lr;
        float* op = out + ((size_t)(b * 256 + q_lane)) * HS_;
        #pragma unroll
        for (int n = 0; n < 4; ++n)
            #pragma unroll
            for (int r = 0; r < 4; ++r)
                op[n * 16 + hi * 4 + r] = acc_o[n][r] * inv;
    }
}

// ---------- launch ----------
extern "C" void kernel_launch(void* const* d_in, const int* in_sizes, int n_in,
                              void* d_out, int out_size, void* d_ws, size_t ws_size,
                              hipStream_t stream) {
    const float* X  = (const float*)d_in[0];
    const float* Wq = (const float*)d_in[1];
    const float* Wk = (const float*)d_in[2];
    const float* Wv = (const float*)d_in[3];
    float* out = (float*)d_out;

    unsigned short* Wfrag = (unsigned short*)d_ws;   // 12*4*3*64*8 u16 = 144 KB

    prep_wfrag<<<36, 256, 0, stream>>>(Wq, Wk, Wv, Wfrag);
    head_fused<<<B_, 1024, 0, stream>>>(X, Wfrag, out);
}

// Round 8
// 36.038 us; speedup vs baseline: 1.3321x; 1.0120x over previous
//
#include <hip/hip_runtime.h>
#include <hip/hip_bf16.h>

#define B_  256
#define T_  256
#define C_  384
#define HS_ 64
#define BT_ (B_*T_)

typedef __attribute__((ext_vector_type(8))) short short8;
typedef __attribute__((ext_vector_type(4))) float f32x4;

// ---------- helpers ----------
__device__ __forceinline__ unsigned short f2bf(float f) {
    unsigned u = __float_as_uint(f);
    u += 0x7FFFu + ((u >> 16) & 1u);   // round-to-nearest-even
    return (unsigned short)(u >> 16);
}

// ---------- kernel 0: W -> MFMA-fragment-ordered bf16 ----------
// Wfrag[s][wn][f][lane] (short8): the exact B-fragment wave (wm,wn) needs at
// K-step s, frag f. Element: col n = wn*48+f*16+(lane&15), k = s*32+(lane>>4)*8+j.
// Q columns pre-scaled by 384^-0.5 (reference scales scores by C^-0.5).
__global__ __launch_bounds__(256) void prep_wfrag(
    const float* __restrict__ Wq, const float* __restrict__ Wk,
    const float* __restrict__ Wv, unsigned short* __restrict__ Wfrag)
{
    const int tid  = blockIdx.x * 256 + threadIdx.x;   // 9216 threads
    const int lane = tid & 63;
    const int q    = tid >> 6;
    const int f    = q % 3;
    const int q2   = q / 3;
    const int wn   = q2 & 3;
    const int s    = q2 >> 2;

    const int n     = wn * 48 + f * 16 + (lane & 15);
    const int kbase = s * 32 + (lane >> 4) * 8;
    const float* src = (n < 64) ? Wq : (n < 128) ? Wk : Wv;
    const int c      = n & 63;
    const float scale = (n < 64) ? 0.05103103630798288f : 1.0f;

    short8 out;
    #pragma unroll
    for (int j = 0; j < 8; ++j)
        out[j] = (short)f2bf(src[(size_t)(kbase + j) * HS_ + c] * scale);
    *(short8*)&Wfrag[(size_t)tid * 8] = out;
}

// ---------- fused kernel: QKV projection + causal flash attention ----------
// One block per batch, 1024 thr = 16 waves (4 waves/SIMD).
// GEMM: M=256 x N=192 x K=384; wave (wm,wn) owns rows wm*64..+64, cols wn*48..+48.
// X staging is depth-2 pipelined (issue s+2, write s+1) so the ds_write's
// vmcnt wait is on loads issued a full step earlier (T14 depth-2).
// Attention (swapped-MFMA): QK^T = mfma(K,Q) -> lane holds P row q=lo;
// in-lane softmax (4 shfls/step) + defer-max (T13); PV = mfma(V,P) -> O^T.
// LDS map (u16 units):
//   Qs  [256][72]  @ 0       (18432)
//   Ks  [256][72]  @ 18432   (18432)
//   Vts [64][264]  @ 36864   (16896)   V transposed: [h][tok]
//   Xs  [2][256][40] @ 53760 (20480)   GEMM staging; P aliases it in attn
// total 74240 u16 = 148480 B
#define LQ_OFF 0
#define LK_OFF 18432
#define LV_OFF 36864
#define LX_OFF 53760
#define LDSP   40

__global__ __launch_bounds__(1024, 4) void head_fused(
    const float* __restrict__ X, const unsigned short* __restrict__ Wfrag,
    float* __restrict__ out)
{
    __shared__ unsigned short lds[74240];
    const int t    = threadIdx.x;
    const int w    = t >> 6;        // 0..15
    const int lane = t & 63;
    const int lo   = lane & 15;
    const int hi   = lane >> 4;
    const int b    = blockIdx.x;
    const int wm   = w >> 2, wn = w & 3;

    const float* Xb = X + (size_t)b * T_ * C_;
    const short8* Wf = (const short8*)Wfrag;

    // ================= phase 1: QKV GEMM =================
    const int srow  = t >> 2;       // 0..255
    const int squad = t & 3;        // 8-float chunk of the 32-k slice

    auto stage_load = [&](int k0, float4* g) {
        const float* p = Xb + (size_t)srow * C_ + k0 + squad * 8;
        g[0] = *(const float4*)(p);
        g[1] = *(const float4*)(p + 4);
    };
    auto stage_write = [&](int buf, const float4* g) {
        short8 p;
        p[0] = (short)f2bf(g[0].x); p[1] = (short)f2bf(g[0].y);
        p[2] = (short)f2bf(g[0].z); p[3] = (short)f2bf(g[0].w);
        p[4] = (short)f2bf(g[1].x); p[5] = (short)f2bf(g[1].y);
        p[6] = (short)f2bf(g[1].z); p[7] = (short)f2bf(g[1].w);
        *(short8*)&lds[LX_OFF + buf * 10240 + srow * 40 + squad * 8] = p;
    };
    auto load_w = [&](int s, short8* wf) {      // coalesced fragment loads
        const short8* base = Wf + ((size_t)(s * 4 + wn) * 3) * 64 + lane;
        #pragma unroll
        for (int f = 0; f < 3; ++f)
            wf[f] = base[f * 64];
    };

    float4 gx[2][2];                 // depth-2 X pipeline: two reg sets in flight
    short8 wfr[2][3];                // W: current / next
    stage_load(0, gx[0]);
    load_w(0, wfr[0]);
    stage_load(32, gx[1]);           // s=1 X in flight
    stage_write(0, gx[0]);           // write s=0 (counted vmcnt: s=1 stays out)
    __syncthreads();

    f32x4 acc[4][3];
    #pragma unroll
    for (int m = 0; m < 4; ++m)
        #pragma unroll
        for (int f = 0; f < 3; ++f)
            acc[m][f] = (f32x4){0.f, 0.f, 0.f, 0.f};

    #pragma unroll 2
    for (int s = 0; s < 12; ++s) {
        const int cur = s & 1;
        if (s < 10) stage_load((s + 2) * 32, gx[cur]);     // issue 2 ahead
        if (s < 11) load_w(s + 1, wfr[cur ^ 1]);           // W 1 ahead
        if (s < 11) stage_write(cur ^ 1, gx[cur ^ 1]);     // write s+1 (arrived)

        short8 af[4];                               // A-frag: row=lo, k=hi*8+j
        #pragma unroll
        for (int m = 0; m < 4; ++m)
            af[m] = *(const short8*)&lds[LX_OFF + cur * 10240 + (wm * 64 + m * 16 + lo) * 40 + hi * 8];
        #pragma unroll
        for (int m = 0; m < 4; ++m)
            #pragma unroll
            for (int f = 0; f < 3; ++f)
                acc[m][f] = __builtin_amdgcn_mfma_f32_16x16x32_bf16(af[m], wfr[cur][f], acc[m][f], 0, 0, 0);
        __syncthreads();
    }

    // epilogue: D col = wn*48+f*16+lo, row = wm*64+m*16+hi*4+r  -> LDS Q/K/Vt
    #pragma unroll
    for (int m = 0; m < 4; ++m) {
        const int rowb = wm * 64 + m * 16 + hi * 4;
        #pragma unroll
        for (int f = 0; f < 3; ++f) {
            const int base = wn * 48 + f * 16;      // frag fully inside one of Q/K/V
            if (base < 64) {
                #pragma unroll
                for (int r = 0; r < 4; ++r)
                    lds[LQ_OFF + (rowb + r) * 72 + base + lo] = f2bf(acc[m][f][r]);
            } else if (base < 128) {
                #pragma unroll
                for (int r = 0; r < 4; ++r)
                    lds[LK_OFF + (rowb + r) * 72 + (base - 64) + lo] = f2bf(acc[m][f][r]);
            } else {
                ushort4 pk = { f2bf(acc[m][f][0]), f2bf(acc[m][f][1]),
                               f2bf(acc[m][f][2]), f2bf(acc[m][f][3]) };
                *(ushort4*)&lds[LV_OFF + (base - 128 + lo) * 264 + rowb] = pk;
            }
        }
    }
    __syncthreads();

    // ================= phase 2: causal flash attention (swapped MFMA) =================
    unsigned short* Pw = &lds[LX_OFF + w * 640];    // per-wave P tile [16][LDSP]

    // SIMD-balanced tile assignment (wave->SIMD assumed w&3):
    // SIMD g gets tiles {g, 15-g, 4+g, 11-g} -> 18 kv-steps each.
    const int sg  = w & 3, pos = w >> 2;
    const int tq  = (pos == 0) ? sg : (pos == 1) ? 15 - sg : (pos == 2) ? 4 + sg : 11 - sg;

    {
        const int q_lane = tq * 16 + lo;            // this lane's q row
        // Q as B-frag: col=q=lo, k=hi*8+j (+32)
        short8 qf0 = *(const short8*)&lds[LQ_OFF + q_lane * 72 + hi * 8];
        short8 qf1 = *(const short8*)&lds[LQ_OFF + q_lane * 72 + hi * 8 + 32];

        f32x4 acc_o[4];                             // O^T: acc_o[n2][r] = O[h=n2*16+hi*4+r][q=lo]
        #pragma unroll
        for (int n = 0; n < 4; ++n) acc_o[n] = (f32x4){0.f, 0.f, 0.f, 0.f};
        float Mr = -1e30f, Lr = 0.f;

        const int nsteps = (tq >> 1) + 1;
        for (int s = 0; s < nsteps; ++s) {
            const int kv0 = s * 32;
            // QK^T swapped: sb[n] = K-rows x Q-cols; D[row=kv][col=q]
            f32x4 sb[2];
            sb[0] = (f32x4){0.f, 0.f, 0.f, 0.f};
            sb[1] = (f32x4){0.f, 0.f, 0.f, 0.f};
            __builtin_amdgcn_s_setprio(1);
            #pragma unroll
            for (int n = 0; n < 2; ++n) {
                const unsigned short* kb = &lds[LK_OFF + (kv0 + n * 16 + lo) * 72 + hi * 8];
                short8 kf0 = *(const short8*)kb;
                short8 kf1 = *(const short8*)(kb + 32);
                sb[n] = __builtin_amdgcn_mfma_f32_16x16x32_bf16(kf0, qf0, sb[n], 0, 0, 0);
                sb[n] = __builtin_amdgcn_mfma_f32_16x16x32_bf16(kf1, qf1, sb[n], 0, 0, 0);
            }
            __builtin_amdgcn_s_setprio(0);
            if (s == nsteps - 1) {                  // causal: kv = kv0+n*16+hi*4+r
                #pragma unroll
                for (int n = 0; n < 2; ++n)
                    #pragma unroll
                    for (int r = 0; r < 4; ++r)
                        if (kv0 + n * 16 + hi * 4 + r > q_lane) sb[n][r] = -1e30f;
            }
            // in-lane softmax for row q=lo (8 values here, rest across hi groups)
            float pmax = fmaxf(fmaxf(fmaxf(sb[0][0], sb[0][1]), fmaxf(sb[0][2], sb[0][3])),
                               fmaxf(fmaxf(sb[1][0], sb[1][1]), fmaxf(sb[1][2], sb[1][3])));
            pmax = fmaxf(pmax, __shfl_xor(pmax, 16));
            pmax = fmaxf(pmax, __shfl_xor(pmax, 32));
            float Mn;
            if (__all(pmax - Mr <= 8.0f)) {         // T13 defer-max: skip rescale
                Mn = Mr;
            } else {
                Mn = fmaxf(Mr, pmax);
                const float fr = __expf(Mr - Mn);
                Mr = Mn;
                Lr *= fr;
                #pragma unroll
                for (int n = 0; n < 4; ++n) {
                    acc_o[n][0] *= fr; acc_o[n][1] *= fr;
                    acc_o[n][2] *= fr; acc_o[n][3] *= fr;
                }
            }
            float p0 = __expf(sb[0][0] - Mn), p1 = __expf(sb[0][1] - Mn);
            float p2 = __expf(sb[0][2] - Mn), p3 = __expf(sb[0][3] - Mn);
            float p4 = __expf(sb[1][0] - Mn), p5 = __expf(sb[1][1] - Mn);
            float p6 = __expf(sb[1][2] - Mn), p7 = __expf(sb[1][3] - Mn);
            float ls = ((p0 + p1) + (p2 + p3)) + ((p4 + p5) + (p6 + p7));
            ls += __shfl_xor(ls, 16);
            ls += __shfl_xor(ls, 32);
            Lr += ls;
            // P -> per-wave LDS tile [q=lo][kv], two b64 writes
            ushort4 w0 = { f2bf(p0), f2bf(p1), f2bf(p2), f2bf(p3) };
            ushort4 w1 = { f2bf(p4), f2bf(p5), f2bf(p6), f2bf(p7) };
            *(ushort4*)&Pw[lo * LDSP + hi * 4]      = w0;
            *(ushort4*)&Pw[lo * LDSP + 16 + hi * 4] = w1;
            // PV swapped: A = Vt rows (h), B = P (col=q); D[row=h][col=q]
            short8 pf = *(const short8*)&Pw[lo * LDSP + hi * 8];
            __builtin_amdgcn_s_setprio(1);
            #pragma unroll
            for (int n = 0; n < 4; ++n) {
                short8 vf = *(const short8*)&lds[LV_OFF + (n * 16 + lo) * 264 + kv0 + hi * 8];
                acc_o[n] = __builtin_amdgcn_mfma_f32_16x16x32_bf16(vf, pf, acc_o[n], 0, 0, 0);
            }
            __builtin_amdgcn_s_setprio(0);
        }
        // epilogue: out[q=q_lane][h=n2*16+hi*4+r] = acc_o[n2][r]/Lr
        const float inv = 1.0f / Lr;
        float* op = out + ((size_t)(b * 256 + q_lane)) * HS_;
        #pragma unroll
        for (int n = 0; n < 4; ++n)
            #pragma unroll
            for (int r = 0; r < 4; ++r)
                op[n * 16 + hi * 4 + r] = acc_o[n][r] * inv;
    }
}

// ---------- launch ----------
extern "C" void kernel_launch(void* const* d_in, const int* in_sizes, int n_in,
                              void* d_out, int out_size, void* d_ws, size_t ws_size,
                              hipStream_t stream) {
    const float* X  = (const float*)d_in[0];
    const float* Wq = (const float*)d_in[1];
    const float* Wk = (const float*)d_in[2];
    const float* Wv = (const float*)d_in[3];
    float* out = (float*)d_out;

    unsigned short* Wfrag = (unsigned short*)d_ws;   // 12*4*3*64*8 u16 = 144 KB

    prep_wfrag<<<36, 256, 0, stream>>>(Wq, Wk, Wv, Wfrag);
    head_fused<<<B_, 1024, 0, stream>>>(X, Wfrag, out);
}